// Round 1
// baseline (229.591 us; speedup 1.0000x reference)
//
#include <hip/hip_runtime.h>

typedef __bf16 bf16x8 __attribute__((ext_vector_type(8)));
typedef float f32x4 __attribute__((ext_vector_type(4)));

__device__ __forceinline__ unsigned short f2bf(float x) {
  union { float f; unsigned int i; } u; u.f = x;
  return (unsigned short)((u.i + 0x7FFFu + ((u.i >> 16) & 1u)) >> 16);
}

// Convert h (f32) -> bf16 table in ws. 8 elems/thread.
__global__ void prep_h_kernel(const float4* __restrict__ h, uint4* __restrict__ o, int n8) {
  int i = blockIdx.x * blockDim.x + threadIdx.x;
  int st = gridDim.x * blockDim.x;
  for (; i < n8; i += st) {
    float4 a = h[2 * i], b = h[2 * i + 1];
    union { unsigned short u[8]; uint4 v; } r;
    r.u[0] = f2bf(a.x); r.u[1] = f2bf(a.y); r.u[2] = f2bf(a.z); r.u[3] = f2bf(a.w);
    r.u[4] = f2bf(b.x); r.u[5] = f2bf(b.y); r.u[6] = f2bf(b.z); r.u[7] = f2bf(b.w);
    o[i] = r.v;
  }
}

__device__ __forceinline__ bf16x8 cvt8(float4 a, float4 b) {
  union { unsigned short u[8]; bf16x8 v; } r;
  r.u[0] = f2bf(a.x); r.u[1] = f2bf(a.y); r.u[2] = f2bf(a.z); r.u[3] = f2bf(a.w);
  r.u[4] = f2bf(b.x); r.u[5] = f2bf(b.y); r.u[6] = f2bf(b.z); r.u[7] = f2bf(b.w);
  return r.v;
}

// Fused gather + MLP.
// Block: 512 threads = 8 waves. Block tile = 512 triplet rows; wave tile = 64 rows (4 m-subtiles of 16).
// GEMM1: M=rows(triplets), N=128 (hid), K=384 (3 concatenated h-rows). 12 K-steps of 32.
// A-frag: lane reads 8 contiguous bf16 of h-row (l&15) directly from global (no LDS).
// B-frag: W1 packed to fragment order in LDS (96 KB), ds_read_b128 conflict-free.
// Epilogue: bias+relu+layer2 in VALU, shfl_xor reduce over 16 col-lanes.
template <bool HBF16>
__global__ __launch_bounds__(512, 2) void fused_kernel(
    const void* __restrict__ Hsrc, const int* __restrict__ trip,
    const float* __restrict__ W1w, const float* __restrict__ b1,
    const float* __restrict__ W2w, const float* __restrict__ b2,
    float* __restrict__ out, int T) {
  extern __shared__ unsigned short w1p[];  // 6144 frags * 8 ushort = 96 KB
  const int tid = threadIdx.x;

  // ---- pack W1[128][384] f32 -> LDS bf16 fragments: frag f = (kk*8+nf)*64+lane,
  // value j = W1[nf*16 + (lane&15)][kk*32 + (lane>>4)*8 + j]
  for (int f = tid; f < 6144; f += 512) {
    int kk = f >> 9;
    int nf = (f >> 6) & 7;
    int ln = f & 63;
    int row = nf * 16 + (ln & 15);
    int k0 = kk * 32 + (ln >> 4) * 8;
    const float* src = W1w + row * 384 + k0;
    float4 a = *(const float4*)src;
    float4 b = *(const float4*)(src + 4);
    union { unsigned short u[8]; uint4 v; } r;
    r.u[0] = f2bf(a.x); r.u[1] = f2bf(a.y); r.u[2] = f2bf(a.z); r.u[3] = f2bf(a.w);
    r.u[4] = f2bf(b.x); r.u[5] = f2bf(b.y); r.u[6] = f2bf(b.z); r.u[7] = f2bf(b.w);
    *(uint4*)&w1p[f * 8] = r.v;
  }
  __syncthreads();

  const int lane = tid & 63;
  const int wv = tid >> 6;      // wave 0..7
  const int l15 = lane & 15;
  const int lg = lane >> 4;     // 0..3

  // per-lane epilogue weights: column c = nf*16 + l15
  float b1r[8], w20[8], w21[8];
#pragma unroll
  for (int nf = 0; nf < 8; nf++) {
    int c = nf * 16 + l15;
    b1r[nf] = b1[c];
    w20[nf] = W2w[c];
    w21[nf] = W2w[128 + c];
  }
  const float bb0 = b2[0], bb1 = b2[1];

  const int ntiles = (T + 511) >> 9;
  for (int tile = blockIdx.x; tile < ntiles; tile += gridDim.x) {
    const int base = tile * 512 + wv * 64;

    f32x4 acc[4][8];
#pragma unroll
    for (int m = 0; m < 4; m++)
#pragma unroll
      for (int nf = 0; nf < 8; nf++) acc[m][nf] = (f32x4){0.f, 0.f, 0.f, 0.f};

    // gather indices for this wave's 64 rows (A-row = l15 within each m-subtile)
    int off[4][3];
#pragma unroll
    for (int m = 0; m < 4; m++) {
      int row = base + m * 16 + l15;
      int rc = row < T ? row : T - 1;
      off[m][0] = trip[rc * 3 + 0];
      off[m][1] = trip[rc * 3 + 1];
      off[m][2] = trip[rc * 3 + 2];
    }

#pragma unroll
    for (int part = 0; part < 3; part++) {
#pragma unroll
      for (int kq = 0; kq < 4; kq++) {
        const int kk = part * 4 + kq;
        bf16x8 af[4];
#pragma unroll
        for (int m = 0; m < 4; m++) {
          if (HBF16) {
            const unsigned short* p =
                (const unsigned short*)Hsrc + ((size_t)off[m][part] << 7) + kq * 32 + lg * 8;
            af[m] = __builtin_bit_cast(bf16x8, *(const uint4*)p);
          } else {
            const float* p =
                (const float*)Hsrc + ((size_t)off[m][part] << 7) + kq * 32 + lg * 8;
            af[m] = cvt8(*(const float4*)p, *(const float4*)(p + 4));
          }
        }
#pragma unroll
        for (int nf = 0; nf < 8; nf++) {
          bf16x8 bf = __builtin_bit_cast(bf16x8,
              *(const uint4*)&w1p[(size_t)(kk * 512 + nf * 64 + lane) * 8]);
#pragma unroll
          for (int m = 0; m < 4; m++)
            acc[m][nf] = __builtin_amdgcn_mfma_f32_16x16x32_bf16(af[m], bf, acc[m][nf], 0, 0, 0);
        }
      }
    }

    // ---- epilogue: hid = relu(acc + b1); out = hid @ W2^T + b2
    // D layout: row = lg*4 + r, col = nf*16 + l15
#pragma unroll
    for (int m = 0; m < 4; m++) {
      float p0[4] = {0.f, 0.f, 0.f, 0.f}, p1[4] = {0.f, 0.f, 0.f, 0.f};
#pragma unroll
      for (int nf = 0; nf < 8; nf++) {
#pragma unroll
        for (int r = 0; r < 4; r++) {
          float hv = fmaxf(acc[m][nf][r] + b1r[nf], 0.f);
          p0[r] = fmaf(hv, w20[nf], p0[r]);
          p1[r] = fmaf(hv, w21[nf], p1[r]);
        }
      }
      // reduce across the 16 column-lanes (butterfly: all lanes end with the sum)
#pragma unroll
      for (int d = 1; d < 16; d <<= 1) {
#pragma unroll
        for (int r = 0; r < 4; r++) {
          p0[r] += __shfl_xor(p0[r], d);
          p1[r] += __shfl_xor(p1[r], d);
        }
      }
#pragma unroll
      for (int r = 0; r < 4; r++) {
        if (l15 == r) {
          int row = base + m * 16 + lg * 4 + r;
          if (row < T) {
            float2 o;
            o.x = p0[r] + bb0;
            o.y = p1[r] + bb1;
            *(float2*)(out + (size_t)row * 2) = o;
          }
        }
      }
    }
  }
}

extern "C" void kernel_launch(void* const* d_in, const int* in_sizes, int n_in,
                              void* d_out, int out_size, void* d_ws, size_t ws_size,
                              hipStream_t stream) {
  const float* h = (const float*)d_in[0];
  const int* trip = (const int*)d_in[1];
  const float* W1w = (const float*)d_in[2];
  const float* b1 = (const float*)d_in[3];
  const float* W2w = (const float*)d_in[4];
  const float* b2 = (const float*)d_in[5];
  float* out = (float*)d_out;

  const int T = in_sizes[1] / 3;
  const size_t hbytes = (size_t)in_sizes[0] * 2;  // bf16 table
  const size_t lds_bytes = 6144 * 16;             // 96 KB

  if (ws_size >= hbytes) {
    int n8 = in_sizes[0] / 8;
    prep_h_kernel<<<2048, 256, 0, stream>>>((const float4*)h, (uint4*)d_ws, n8);
    fused_kernel<true><<<256, 512, lds_bytes, stream>>>(d_ws, trip, W1w, b1, W2w, b2, out, T);
  } else {
    fused_kernel<false><<<256, 512, lds_bytes, stream>>>(h, trip, W1w, b1, W2w, b2, out, T);
  }
}